// Round 4
// baseline (2228.715 us; speedup 1.0000x reference)
//
#include <hip/hip_runtime.h>

typedef float v2f __attribute__((ext_vector_type(2)));
typedef float v4f __attribute__((ext_vector_type(4)));

#define LOG2E 1.4426950408889634f
#define LN2   0.6931471805599453f

__device__ __forceinline__ float fexp2(float x) {
  float r; asm("v_exp_f32 %0, %1" : "=v"(r) : "v"(x)); return r;
}
__device__ __forceinline__ float frcp(float x) {
  float r; asm("v_rcp_f32 %0, %1" : "=v"(r) : "v"(x)); return r;
}
__device__ __forceinline__ float flog2(float x) {
  float r; asm("v_log_f32 %0, %1" : "=v"(r) : "v"(x)); return r;
}
// packed fp32 FMA, accumulator in-place ("+v" avoids copies)
__device__ __forceinline__ void pkfma(v2f& c, v2f a, v2f b) {
  asm("v_pk_fma_f32 %0, %1, %2, %0" : "+v"(c) : "v"(a), "v"(b));
}
// quad_perm xor1 lane swap on the VALU pipe
__device__ __forceinline__ float dpp_xor1(float v) {
  return __builtin_bit_cast(float,
      __builtin_amdgcn_update_dpp(0, __builtin_bit_cast(int, v), 0xB1, 0xF, 0xF, true));
}
// workgroup barrier WITHOUT vmcnt(0) drain: LDS ordering only.
__device__ __forceinline__ void barrier_lgkm() {
  asm volatile("s_waitcnt lgkmcnt(0)\n\ts_barrier" ::: "memory");
}

// ---------------- embedding concat ------------------------------------------------
__global__ void k_embed(const float* __restrict__ wv, const int* __restrict__ pidx,
                        const float* __restrict__ pemb, float* __restrict__ X) {
  int t = blockIdx.x;
  int pi = pidx[t];
  for (int c = threadIdx.x; c < 336; c += 128) {
    float v;
    if (c < 300)      v = wv[t * 300 + c];
    else if (c < 325) v = pemb[pi * 25 + (c - 300)];
    else              v = 0.f;
    X[t * 336 + c] = v;
  }
}

// ---------------- row repack with zero K-pad; optional exp2 half-scale -------------
// scale = 0.5*LOG2E (sigmoid gates) / LOG2E (g-gate): the 0.5 is because BOTH
// dpp-reduce lanes add the pre-gate term in k_rec.
__global__ void k_repack(const float* __restrict__ src, float* __restrict__ dst,
                         int sK, int dK, int doScale) {
  int r = blockIdx.x;
  float sc = 1.f;
  if (doScale) { int gate = (r % 500) / 125; sc = (gate == 2) ? LOG2E : 0.5f * LOG2E; }
  for (int c = threadIdx.x; c < dK; c += 128)
    dst[r * dK + c] = (c < sK) ? src[r * sK + c] * sc : 0.f;
}

// ---------------- bias half-scale (exp2 domain, per gate) --------------------------
__global__ void k_bscale(const float* __restrict__ b, float* __restrict__ bs) {
  int i = blockIdx.x * 256 + threadIdx.x;
  if (i < 1000) {
    int gate = (i % 500) / 125;
    bs[i] = b[i] * ((gate == 2) ? LOG2E : 0.5f * LOG2E);
  }
}

// ---------------- split fc1_W [100][500] -> Wab [200][256] ------------------------
__global__ void k_wab(const float* __restrict__ fc1W, float* __restrict__ Wab) {
  int r = blockIdx.x;                       // 0..199
  int sr = (r < 100) ? r : r - 100;
  int so = (r < 100) ? 0 : 250;
  for (int c = threadIdx.x; c < 256; c += 128)
    Wab[r * 256 + c] = (c < 250) ? fc1W[sr * 500 + so + c] : 0.f;
}

// ---------------- biasAB + sum(fc2_W) ----------------------------------------------
__global__ void k_misc(const float* __restrict__ fc1b, const float* __restrict__ fc2W,
                       float* __restrict__ biasAB, float* __restrict__ sumw) {
  __shared__ float red[128];
  int t = threadIdx.x;   // 128 threads
  for (int c = t; c < 256; c += 128)
    biasAB[c] = (c < 100) ? fc1b[c] : 0.f;
  float s = (t < 100) ? fc2W[t] : 0.f;
  red[t] = s; __syncthreads();
  for (int off = 64; off; off >>= 1) {
    if (t < off) red[t] += red[t + off];
    __syncthreads();
  }
  if (t == 0) sumw[0] = red[0];
}

// ---------------- tiled fp32 GEMM:  C = A @ B^T + bias -----------------------------
#define BM 64
#define BN 64
#define BKK 16
__global__ __launch_bounds__(256) void k_gemm(
    const float* __restrict__ A, const float* __restrict__ Bw,
    const float* __restrict__ bias, float* __restrict__ C,
    int M, int N, int K, int ldC, long sBz, long sCz, long sbz, int transOut) {
  const int z = blockIdx.z;
  const float* Bp = Bw + (size_t)z * sBz;
  const float* bp = bias + (size_t)z * sbz;
  float* Cp = C + (size_t)z * sCz;
  const int bm = blockIdx.y * BM, bn = blockIdx.x * BN;
  __shared__ __align__(16) float As[BKK][BM + 4];
  __shared__ __align__(16) float Bs[BKK][BN + 4];
  __shared__ float Ts[BN][BM + 1];
  const int tid = threadIdx.x;
  const int tx = tid & 15, ty = tid >> 4;
  const int lr = tid >> 2;            // 0..63
  const int lk = (tid & 3) * 4;       // 0,4,8,12
  float acc[4][4];
#pragma unroll
  for (int a = 0; a < 4; ++a)
#pragma unroll
    for (int b = 0; b < 4; ++b) acc[a][b] = 0.f;

  int brow = bn + lr; if (brow >= N) brow = N - 1;
  for (int k0 = 0; k0 < K; k0 += BKK) {
    float4 a4 = *(const float4*)(A + (size_t)(bm + lr) * K + k0 + lk);
    float4 b4 = *(const float4*)(Bp + (size_t)brow * K + k0 + lk);
    __syncthreads();
    As[lk + 0][lr] = a4.x; As[lk + 1][lr] = a4.y; As[lk + 2][lr] = a4.z; As[lk + 3][lr] = a4.w;
    Bs[lk + 0][lr] = b4.x; Bs[lk + 1][lr] = b4.y; Bs[lk + 2][lr] = b4.z; Bs[lk + 3][lr] = b4.w;
    __syncthreads();
#pragma unroll
    for (int kk = 0; kk < BKK; ++kk) {
      float4 av = *(const float4*)&As[kk][ty * 4];
      float4 bv = *(const float4*)&Bs[kk][tx * 4];
      float aa[4] = {av.x, av.y, av.z, av.w};
      float bb[4] = {bv.x, bv.y, bv.z, bv.w};
#pragma unroll
      for (int a = 0; a < 4; ++a)
#pragma unroll
        for (int b = 0; b < 4; ++b)
          acc[a][b] = __builtin_fmaf(aa[a], bb[b], acc[a][b]);
    }
  }
  if (!transOut) {
#pragma unroll
    for (int a = 0; a < 4; ++a) {
      int i = bm + ty * 4 + a;
#pragma unroll
      for (int b = 0; b < 4; ++b) {
        int j = bn + tx * 4 + b;
        if (j < N) Cp[(size_t)i * ldC + j] = acc[a][b] + bp[j];
      }
    }
  } else {
    __syncthreads();
#pragma unroll
    for (int a = 0; a < 4; ++a)
#pragma unroll
      for (int b = 0; b < 4; ++b) {
        int jn = bn + tx * 4 + b; if (jn >= N) jn = N - 1;
        Ts[tx * 4 + b][ty * 4 + a] = acc[a][b] + bp[jn];
      }
    __syncthreads();
    const int n2 = tid >> 2, mq = (tid & 3) * 16;
    const int n = bn + n2;
    if (n < N) {
#pragma unroll
      for (int r = 0; r < 4; ++r) {
        int m0 = mq + r * 4;
        float4 v;
        v.x = Ts[n2][m0 + 0]; v.y = Ts[n2][m0 + 1];
        v.z = Ts[n2][m0 + 2]; v.w = Ts[n2][m0 + 3];
        *(float4*)(Cp + (size_t)n * ldC + bm + m0) = v;
      }
    }
  }
}

// ---------------- LSTM recurrence v4 ----------------------------------------------
// Pt: [d][500][1024] pre-gates (x@Wih^T+b), pre-scaled 0.5*LOG2E (LOG2E for g-gate).
// 256 threads = 4 waves (1/SIMD, 512-VGPR budget): thread (u=t>>1, sub=t&1) owns
// ALL 4 gate rows of unit u over cols sub*64..+63 -> 256 weight VGPRs in arch file.
// One dpp_xor1 reduce per gate; activations fully in-lane; 1 lgkm barrier/step.
__device__ __forceinline__ float elem(float4 v, int e) {
  return (e == 0) ? v.x : (e == 1) ? v.y : (e == 2) ? v.z : v.w;
}

template<bool FWD>
__device__ __forceinline__ void rec_loop(
    const float4* __restrict__ P0, const float4* __restrict__ P1,
    const float4* __restrict__ P2, const float4* __restrict__ P3,
    const v2f (&w)[4][32], float (*hb)[128], float (*hist)[128],
    float* __restrict__ hout, int d, int t, int u, int sub, bool wr) {
  float cst = 0.f;
  float4 cur0 = P0[FWD ? 0 : 255], cur1 = P1[FWD ? 0 : 255];
  float4 cur2 = P2[FWD ? 0 : 255], cur3 = P3[FWD ? 0 : 255];
  barrier_lgkm();

  for (int cb = 0; cb < 256; ++cb) {
    int nc = (cb + 1 < 256) ? cb + 1 : cb;
    int ni = FWD ? nc : 255 - nc;
    float4 nxt0 = P0[ni], nxt1 = P1[ni], nxt2 = P2[ni], nxt3 = P3[ni];
#pragma unroll
    for (int e = 0; e < 4; ++e) {
      const int buf = e & 1;
      const int ee = FWD ? e : 3 - e;
      float pr0 = elem(cur0, ee), pr1 = elem(cur1, ee);
      float pr2 = elem(cur2, ee), pr3 = elem(cur3, ee);
      const v4f* hp = (const v4f*)&hb[buf][sub * 64];
      v2f a0 = {0.f, 0.f}, a1 = {0.f, 0.f}, a2 = {0.f, 0.f}, a3 = {0.f, 0.f};
#pragma unroll
      for (int q = 0; q < 16; ++q) {
        v4f hv = hp[q];
        v2f ha = __builtin_shufflevector(hv, hv, 0, 1);
        v2f hc = __builtin_shufflevector(hv, hv, 2, 3);
        pkfma(a0, w[0][2 * q], ha); pkfma(a0, w[0][2 * q + 1], hc);
        pkfma(a1, w[1][2 * q], ha); pkfma(a1, w[1][2 * q + 1], hc);
        pkfma(a2, w[2][2 * q], ha); pkfma(a2, w[2][2 * q + 1], hc);
        pkfma(a3, w[3][2 * q], ha); pkfma(a3, w[3][2 * q + 1], hc);
      }
      // partial + half pre-gate; dpp reduce-all over the 2 sub lanes (bitwise equal)
      float p0 = a0.x + a0.y + pr0;  p0 += dpp_xor1(p0);
      float p1 = a1.x + a1.y + pr1;  p1 += dpp_xor1(p1);
      float p2 = a2.x + a2.y + pr2;  p2 += dpp_xor1(p2);
      float p3 = a3.x + a3.y + pr3;  p3 += dpp_xor1(p3);
      // gates fully in-lane (exp2 domain)
      float gi = frcp(1.f + fexp2(-p0));
      float gf = frcp(1.f + fexp2(-p1));
      float gg = __builtin_fmaf(2.f, frcp(1.f + fexp2(-p2)), -1.f);
      float go = frcp(1.f + fexp2(-p3));
      cst = __builtin_fmaf(gf, cst, gi * gg);
      float th = __builtin_fmaf(2.f, frcp(1.f + fexp2(-2.f * LOG2E * cst)), -1.f);
      float h = go * th;
      if (wr) {
        hb[buf ^ 1][u] = h;
        hist[(cb & 7) * 4 + e][u] = h;
      }
      barrier_lgkm();
    }
    if ((cb & 7) == 7) {   // flush 32 steps of h (global stores stay in flight)
      const int S0 = 4 * cb - 28;
#pragma unroll
      for (int k = 0; k < 16; ++k) {
        int idx = t + k * 256;
        int r = idx >> 7, u2 = idx & 127;
        if (u2 < 125) {
          int step = S0 + r;
          int time = FWD ? step : 1023 - step;
          hout[(size_t)time * 256 + d * 125 + u2] = hist[r][u2];
        }
      }
      barrier_lgkm();
    }
    cur0 = nxt0; cur1 = nxt1; cur2 = nxt2; cur3 = nxt3;
  }
}

__global__ __launch_bounds__(256, 1) void k_rec(const float* __restrict__ Pt,
                                                const float* __restrict__ Whh,
                                                float* __restrict__ hout) {
  const int d = blockIdx.x;
  const int t = threadIdx.x;
  int u = t >> 1; const bool active = (u < 125); if (u > 124) u = 124;
  const int sub = t & 1;
  const bool wr = (sub == 0) && active;

  // weights: 4 gates x 64 cols (sub half) -> 256 arch VGPRs, unhalved exp2 scale
  const float* Wd = Whh + (size_t)d * 500 * 125;
  v2f w[4][32];
#pragma unroll
  for (int g = 0; g < 4; ++g) {
    const float sc = (g == 2) ? 2.f * LOG2E : LOG2E;
    const float* wrp = Wd + (size_t)(g * 125 + u) * 125;
#pragma unroll
    for (int j = 0; j < 32; ++j) {
      int col = sub * 64 + 2 * j;
      v2f ww;
      ww.x = (col     < 125) ? wrp[col]     * sc : 0.f;
      ww.y = (col + 1 < 125) ? wrp[col + 1] * sc : 0.f;
      w[g][j] = ww;
    }
  }

  __shared__ __align__(16) float hb[2][128];
  __shared__ float hist[32][128];
  ((float*)hb)[t] = 0.f;

  const float4* Pb = (const float4*)(Pt + (size_t)d * 500 * 1024);
  const float4* P0 = Pb + (size_t)(0 * 125 + u) * 256;
  const float4* P1 = Pb + (size_t)(1 * 125 + u) * 256;
  const float4* P2 = Pb + (size_t)(2 * 125 + u) * 256;
  const float4* P3 = Pb + (size_t)(3 * 125 + u) * 256;

  if (d == 0) rec_loop<true >(P0, P1, P2, P3, w, hb, hist, hout, d, t, u, sub, wr);
  else        rec_loop<false>(P0, P1, P2, P3, w, hb, hist, hout, d, t, u, sub, wr);
}

// ---------------- pairwise scorer ---------------------------------------------------
__global__ __launch_bounds__(256) void k_pair(const float* __restrict__ AB,
    const float* __restrict__ fc2W, const float* __restrict__ fc2b,
    const float* __restrict__ sumw, float* __restrict__ outS,
    float* __restrict__ scoresT) {
  __shared__ float As[32][100];
  __shared__ float Bs[32][101];
  __shared__ float w2s[100];
  const int tid = threadIdx.x;
  const int i0 = blockIdx.y * 32, j0 = blockIdx.x * 32;
  for (int idx = tid; idx < 3200; idx += 256) {
    int r = idx / 100, k = idx - r * 100;
    As[r][k] = AB[(size_t)(i0 + r) * 200 + k];
    Bs[r][k] = AB[(size_t)(j0 + r) * 200 + 100 + k];
  }
  if (tid < 100) w2s[tid] = 2.f * fc2W[tid];
  __syncthreads();
  const int tx = tid & 31, ty = tid >> 5;
  float acc[4] = {0.f, 0.f, 0.f, 0.f};
#pragma unroll 4
  for (int k = 0; k < 100; ++k) {
    float b = Bs[tx][k];
    float wk2 = w2s[k];
    float bs = b * (2.f * LOG2E);
#pragma unroll
    for (int q = 0; q < 4; ++q) {
      float a = As[ty + 8 * q][k];
      float r = frcp(1.f + fexp2(__builtin_fmaf(a, 2.f * LOG2E, bs)));
      acc[q] = __builtin_fmaf(wk2, r, acc[q]);
    }
  }
  float base = sumw[0] + fc2b[0];
  const int j = j0 + tx;
#pragma unroll
  for (int q = 0; q < 4; ++q) {
    int i = i0 + ty + 8 * q;
    float val = (i != j && j != 0) ? (base - acc[q]) : 0.f;
    outS[(size_t)i * 1024 + j] = val;
    scoresT[(size_t)j * 1024 + i] = val;
  }
}

// ---------------- per-child log-softmax contribution -------------------------------
__global__ __launch_bounds__(256) void k_soft(const float* __restrict__ scoresT,
    const int* __restrict__ parents, float* __restrict__ contrib) {
  const int j = blockIdx.x, tid = threadIdx.x;
  __shared__ float red[256];
  const float* row = scoresT + (size_t)j * 1024;
  float v0 = row[tid], v1 = row[tid + 256], v2 = row[tid + 512], v3 = row[tid + 768];
  float m = fmaxf(fmaxf(v0, v1), fmaxf(v2, v3));
  red[tid] = m; __syncthreads();
  for (int off = 128; off; off >>= 1) {
    if (tid < off) red[tid] = fmaxf(red[tid], red[tid + off]);
    __syncthreads();
  }
  m = red[0]; __syncthreads();
  float s = fexp2((v0 - m) * LOG2E) + fexp2((v1 - m) * LOG2E) +
            fexp2((v2 - m) * LOG2E) + fexp2((v3 - m) * LOG2E);
  red[tid] = s; __syncthreads();
  for (int off = 128; off; off >>= 1) {
    if (tid < off) red[tid] += red[tid + off];
    __syncthreads();
  }
  if (tid == 0) {
    float S = red[0];
    int p = parents[j];
    contrib[j] = row[p] - m - flog2(S) * LN2;
  }
}

__global__ __launch_bounds__(256) void k_loss(const float* __restrict__ contrib,
                                              float* __restrict__ out) {
  __shared__ float red[256];
  int tid = threadIdx.x;
  float s = contrib[tid] + contrib[tid + 256] + contrib[tid + 512] + contrib[tid + 768];
  red[tid] = s; __syncthreads();
  for (int off = 128; off; off >>= 1) {
    if (tid < off) red[tid] += red[tid + off];
    __syncthreads();
  }
  if (tid == 0) out[0] = -red[0] * (1.f / 1024.f);
}

// ---------------- launcher ---------------------------------------------------------
extern "C" void kernel_launch(void* const* d_in, const int* in_sizes, int n_in,
                              void* d_out, int out_size, void* d_ws, size_t ws_size,
                              hipStream_t stream) {
  const float* wv   = (const float*)d_in[0];
  const int*   pidx = (const int*)d_in[1];
  const int*   par  = (const int*)d_in[2];
  const float* pemb = (const float*)d_in[3];
  const float* Wih0 = (const float*)d_in[4];
  const float* Whh0 = (const float*)d_in[5];
  const float* b0   = (const float*)d_in[6];
  const float* Wih1 = (const float*)d_in[7];
  const float* Whh1 = (const float*)d_in[8];
  const float* b1   = (const float*)d_in[9];
  const float* fc1W = (const float*)d_in[10];
  const float* fc1b = (const float*)d_in[11];
  const float* fc2W = (const float*)d_in[12];
  const float* fc2b = (const float*)d_in[13];
  float* ws = (float*)d_ws;
  // workspace layout (float offsets)
  float* X      = ws + 0;        // 1024*336
  float* Wih0p  = ws + 344064;   // 2*500*336
  float* Pt0    = ws + 680064;   // 2*500*1024
  float* h0     = ws + 1704064;  // 1024*256
  float* Wih1p  = ws + 1966208;  // 2*500*256
  float* Pt1    = ws + 2222208;  // 2*500*1024
  float* h1     = ws + 3246208;  // 1024*256
  float* Wab    = ws + 3508352;  // 200*256
  float* biasAB = ws + 3559552;  // 256
  float* AB     = ws + 3559808;  // 1024*200
  float* scT    = ws + 3764608;  // 1024*1024
  float* contrib= ws + 4813184;  // 1024
  float* sumw   = ws + 4814208;  // 1
  float* bs0    = ws + 4814212;  // 1000 (scaled biases layer 0)
  float* bs1    = ws + 4815212;  // 1000 (scaled biases layer 1)
  float* out = (float*)d_out;

  // zero padded h buffers (cols 250..255 must stay 0 for the K=256 GEMMs)
  hipMemsetAsync(h0, 0, 1024 * 256 * sizeof(float), stream);
  hipMemsetAsync(h1, 0, 1024 * 256 * sizeof(float), stream);

  k_embed <<<1024, 128, 0, stream>>>(wv, pidx, pemb, X);
  k_repack<<<1000, 128, 0, stream>>>(Wih0, Wih0p, 325, 336, 1);
  k_repack<<<1000, 128, 0, stream>>>(Wih1, Wih1p, 250, 256, 1);
  k_bscale<<<4, 256, 0, stream>>>(b0, bs0);
  k_bscale<<<4, 256, 0, stream>>>(b1, bs1);
  k_wab   <<<200, 128, 0, stream>>>(fc1W, Wab);
  k_misc  <<<1, 128, 0, stream>>>(fc1b, fc2W, biasAB, sumw);

  // layer 0 (pre-gates stored transposed: Pt[z][n][m], ldC = 1024)
  k_gemm<<<dim3(8, 16, 2), 256, 0, stream>>>(X, Wih0p, bs0, Pt0, 1024, 500, 336, 1024,
                                             500L * 336, 500L * 1024, 500L, 1);
  k_rec <<<2, 256, 0, stream>>>(Pt0, Whh0, h0);
  // layer 1
  k_gemm<<<dim3(8, 16, 2), 256, 0, stream>>>(h0, Wih1p, bs1, Pt1, 1024, 500, 256, 1024,
                                             500L * 256, 500L * 1024, 500L, 1);
  k_rec <<<2, 256, 0, stream>>>(Pt1, Whh1, h1);
  // head/child projections (fc1_b folded into head half via biasAB)
  k_gemm<<<dim3(4, 16, 1), 256, 0, stream>>>(h1, Wab, biasAB, AB, 1024, 200, 256, 200,
                                             0L, 0L, 0L, 0);
  // pairwise scores + transposed copy
  k_pair<<<dim3(32, 32), 256, 0, stream>>>(AB, fc2W, fc2b, sumw, out + 1, scT);
  // per-child log-softmax and loss
  k_soft<<<1024, 256, 0, stream>>>(scT, par, contrib);
  k_loss<<<1, 256, 0, stream>>>(contrib, out);
}

// Round 5
// 1368.351 us; speedup vs baseline: 1.6288x; 1.6288x over previous
//
#include <hip/hip_runtime.h>

typedef float v2f __attribute__((ext_vector_type(2)));
typedef float v4f __attribute__((ext_vector_type(4)));

#define LOG2E 1.4426950408889634f
#define LN2   0.6931471805599453f

__device__ __forceinline__ float fexp2(float x) {
  float r; asm("v_exp_f32 %0, %1" : "=v"(r) : "v"(x)); return r;
}
__device__ __forceinline__ float fexp2n(float x) {   // exp2(-x), modifier is free
  float r; asm("v_exp_f32 %0, -%1" : "=v"(r) : "v"(x)); return r;
}
__device__ __forceinline__ float frcp(float x) {
  float r; asm("v_rcp_f32 %0, %1" : "=v"(r) : "v"(x)); return r;
}
__device__ __forceinline__ float flog2(float x) {
  float r; asm("v_log_f32 %0, %1" : "=v"(r) : "v"(x)); return r;
}
// packed fp32 FMA, accumulate in place
__device__ __forceinline__ void pkfma(v2f& c, v2f a, v2f b) {
  asm("v_pk_fma_f32 %0, %1, %2, %0" : "+v"(c) : "v"(a), "v"(b));
}
// quad_perm lane swaps (VALU pipe)
__device__ __forceinline__ float dpp_xor1(float v) {
  return __builtin_bit_cast(float,
      __builtin_amdgcn_update_dpp(0, __builtin_bit_cast(int, v), 0xB1, 0xF, 0xF, true));
}
__device__ __forceinline__ float dpp_xor2(float v) {
  return __builtin_bit_cast(float,
      __builtin_amdgcn_update_dpp(0, __builtin_bit_cast(int, v), 0x4E, 0xF, 0xF, true));
}
// workgroup barrier WITHOUT vmcnt(0) drain: LDS ordering only
__device__ __forceinline__ void barrier_lgkm() {
  asm volatile("s_waitcnt lgkmcnt(0)\n\ts_barrier" ::: "memory");
}

// ---------------- embedding concat ------------------------------------------------
__global__ void k_embed(const float* __restrict__ wv, const int* __restrict__ pidx,
                        const float* __restrict__ pemb, float* __restrict__ X) {
  int t = blockIdx.x;
  int pi = pidx[t];
  for (int c = threadIdx.x; c < 336; c += 128) {
    float v;
    if (c < 300)      v = wv[t * 300 + c];
    else if (c < 325) v = pemb[pi * 25 + (c - 300)];
    else              v = 0.f;
    X[t * 336 + c] = v;
  }
}

// ---------------- row repack with zero K-pad; optional exp2 quarter-scale ----------
// quarter because ALL FOUR quad lanes add the pre-gate term before the reduce-all.
__global__ void k_repack(const float* __restrict__ src, float* __restrict__ dst,
                         int sK, int dK, int doScale) {
  int r = blockIdx.x;
  float sc = 1.f;
  if (doScale) { int gate = (r % 500) / 125; sc = (gate == 2) ? 0.5f * LOG2E : 0.25f * LOG2E; }
  for (int c = threadIdx.x; c < dK; c += 128)
    dst[r * dK + c] = (c < sK) ? src[r * sK + c] * sc : 0.f;
}

// ---------------- bias quarter-scale (exp2 domain, per gate) -----------------------
__global__ void k_bscale(const float* __restrict__ b, float* __restrict__ bs) {
  int i = blockIdx.x * 256 + threadIdx.x;
  if (i < 1000) {
    int gate = (i % 500) / 125;
    bs[i] = b[i] * ((gate == 2) ? 0.5f * LOG2E : 0.25f * LOG2E);
  }
}

// ---------------- split fc1_W [100][500] -> Wab [200][256] ------------------------
__global__ void k_wab(const float* __restrict__ fc1W, float* __restrict__ Wab) {
  int r = blockIdx.x;                       // 0..199
  int sr = (r < 100) ? r : r - 100;
  int so = (r < 100) ? 0 : 250;
  for (int c = threadIdx.x; c < 256; c += 128)
    Wab[r * 256 + c] = (c < 250) ? fc1W[sr * 500 + so + c] : 0.f;
}

// ---------------- biasAB + sum(fc2_W) ----------------------------------------------
__global__ void k_misc(const float* __restrict__ fc1b, const float* __restrict__ fc2W,
                       float* __restrict__ biasAB, float* __restrict__ sumw) {
  __shared__ float red[128];
  int t = threadIdx.x;   // 128 threads
  for (int c = t; c < 256; c += 128)
    biasAB[c] = (c < 100) ? fc1b[c] : 0.f;
  float s = (t < 100) ? fc2W[t] : 0.f;
  red[t] = s; __syncthreads();
  for (int off = 64; off; off >>= 1) {
    if (t < off) red[t] += red[t + off];
    __syncthreads();
  }
  if (t == 0) sumw[0] = red[0];
}

// ---------------- tiled fp32 GEMM:  C = A @ B^T + bias -----------------------------
// transOut=0: C[m][n]. transOut=2: gate-interleaved scatter for k_rec:
//   C[(n%125)*4096 + m*4 + (n/125)]   (Pq[u][t][gate] layout, N must be 500, M 1024)
#define BM 64
#define BN 64
#define BKK 16
__global__ __launch_bounds__(256) void k_gemm(
    const float* __restrict__ A, const float* __restrict__ Bw,
    const float* __restrict__ bias, float* __restrict__ C,
    int M, int N, int K, int ldC, long sBz, long sCz, long sbz, int transOut) {
  const int z = blockIdx.z;
  const float* Bp = Bw + (size_t)z * sBz;
  const float* bp = bias + (size_t)z * sbz;
  float* Cp = C + (size_t)z * sCz;
  const int bm = blockIdx.y * BM, bn = blockIdx.x * BN;
  __shared__ __align__(16) float As[BKK][BM + 4];
  __shared__ __align__(16) float Bs[BKK][BN + 4];
  const int tid = threadIdx.x;
  const int tx = tid & 15, ty = tid >> 4;
  const int lr = tid >> 2;            // 0..63
  const int lk = (tid & 3) * 4;       // 0,4,8,12
  float acc[4][4];
#pragma unroll
  for (int a = 0; a < 4; ++a)
#pragma unroll
    for (int b = 0; b < 4; ++b) acc[a][b] = 0.f;

  int brow = bn + lr; if (brow >= N) brow = N - 1;
  for (int k0 = 0; k0 < K; k0 += BKK) {
    float4 a4 = *(const float4*)(A + (size_t)(bm + lr) * K + k0 + lk);
    float4 b4 = *(const float4*)(Bp + (size_t)brow * K + k0 + lk);
    __syncthreads();
    As[lk + 0][lr] = a4.x; As[lk + 1][lr] = a4.y; As[lk + 2][lr] = a4.z; As[lk + 3][lr] = a4.w;
    Bs[lk + 0][lr] = b4.x; Bs[lk + 1][lr] = b4.y; Bs[lk + 2][lr] = b4.z; Bs[lk + 3][lr] = b4.w;
    __syncthreads();
#pragma unroll
    for (int kk = 0; kk < BKK; ++kk) {
      float4 av = *(const float4*)&As[kk][ty * 4];
      float4 bv = *(const float4*)&Bs[kk][tx * 4];
      float aa[4] = {av.x, av.y, av.z, av.w};
      float bb[4] = {bv.x, bv.y, bv.z, bv.w};
#pragma unroll
      for (int a = 0; a < 4; ++a)
#pragma unroll
        for (int b = 0; b < 4; ++b)
          acc[a][b] = __builtin_fmaf(aa[a], bb[b], acc[a][b]);
    }
  }
  if (transOut == 0) {
#pragma unroll
    for (int a = 0; a < 4; ++a) {
      int i = bm + ty * 4 + a;
#pragma unroll
      for (int b = 0; b < 4; ++b) {
        int j = bn + tx * 4 + b;
        if (j < N) Cp[(size_t)i * ldC + j] = acc[a][b] + bp[j];
      }
    }
  } else {
#pragma unroll
    for (int a = 0; a < 4; ++a) {
      int i = bm + ty * 4 + a;      // time
#pragma unroll
      for (int b = 0; b < 4; ++b) {
        int j = bn + tx * 4 + b;    // gate-row
        if (j < N) {
          int g = j / 125, u2 = j - g * 125;
          Cp[(size_t)u2 * 4096 + i * 4 + g] = acc[a][b] + bp[j];
        }
      }
    }
  }
}

// ---------------- LSTM recurrence v5 ----------------------------------------------
// Pq: [d][125][1024][4] quarter-scaled pre-gates {i,f,g,o} per (unit,time).
// Whh: [d][500][125] (scaled LOG2E / 2LOG2E at load). hout: [1024][256].
// 512 threads = 8 waves (2/SIMD): thread (u=t>>2, sub=t&3) owns all 4 gate rows of
// unit u over cols sub*32..+31 (128 weight VGPRs). Quad reduce-all via 2 DPP adds;
// all activations + c,h computed redundantly in-quad; sub0 writes h to LDS + global.
#define REC_BODY(FWD)                                                              \
  {                                                                                \
    float cst = 0.f;                                                               \
    float4 cur[4], nxt[4];                                                         \
    _Pragma("unroll")                                                              \
    for (int e = 0; e < 4; ++e) cur[e] = Pr4[(FWD ? 0 : 1020) + e];                \
    __syncthreads();                                                               \
    for (int cb = 0; cb < 256; ++cb) {                                             \
      int nc = (cb + 1 < 256) ? cb + 1 : cb;                                       \
      int nb = FWD ? 4 * nc : 1020 - 4 * nc;                                       \
      _Pragma("unroll")                                                            \
      for (int e = 0; e < 4; ++e) nxt[e] = Pr4[nb + e];                            \
      _Pragma("unroll")                                                            \
      for (int e = 0; e < 4; ++e) {                                                \
        const int buf = e & 1;                                                     \
        float4 pre = cur[FWD ? e : 3 - e];                                         \
        const v4f* hp = (const v4f*)&hb[buf][36 * sub];                            \
        v2f a0 = {0.f, 0.f}, a1 = {0.f, 0.f}, a2 = {0.f, 0.f}, a3 = {0.f, 0.f};    \
        _Pragma("unroll")                                                          \
        for (int q = 0; q < 4; ++q) {                                              \
          v4f h1v = hp[2 * q], h2v = hp[2 * q + 1];                                \
          v2f ha = __builtin_shufflevector(h1v, h1v, 0, 1);                        \
          v2f hc = __builtin_shufflevector(h1v, h1v, 2, 3);                        \
          v2f he = __builtin_shufflevector(h2v, h2v, 0, 1);                        \
          v2f hg = __builtin_shufflevector(h2v, h2v, 2, 3);                        \
          pkfma(a0, w0[4 * q], ha); pkfma(a0, w0[4 * q + 1], hc);                  \
          pkfma(a0, w0[4 * q + 2], he); pkfma(a0, w0[4 * q + 3], hg);              \
          pkfma(a1, w1[4 * q], ha); pkfma(a1, w1[4 * q + 1], hc);                  \
          pkfma(a1, w1[4 * q + 2], he); pkfma(a1, w1[4 * q + 3], hg);              \
          pkfma(a2, w2[4 * q], ha); pkfma(a2, w2[4 * q + 1], hc);                  \
          pkfma(a2, w2[4 * q + 2], he); pkfma(a2, w2[4 * q + 3], hg);              \
          pkfma(a3, w3[4 * q], ha); pkfma(a3, w3[4 * q + 1], hc);                  \
          pkfma(a3, w3[4 * q + 2], he); pkfma(a3, w3[4 * q + 3], hg);              \
        }                                                                          \
        float p0 = a0.x + a0.y + pre.x;                                            \
        float p1 = a1.x + a1.y + pre.y;                                            \
        float p2 = a2.x + a2.y + pre.z;                                            \
        float p3 = a3.x + a3.y + pre.w;                                            \
        p0 += dpp_xor1(p0); p0 += dpp_xor2(p0);                                    \
        p1 += dpp_xor1(p1); p1 += dpp_xor2(p1);                                    \
        p2 += dpp_xor1(p2); p2 += dpp_xor2(p2);                                    \
        p3 += dpp_xor1(p3); p3 += dpp_xor2(p3);                                    \
        float gi = frcp(1.f + fexp2n(p0));                                         \
        float gf = frcp(1.f + fexp2n(p1));                                         \
        float gg = __builtin_fmaf(2.f, frcp(1.f + fexp2n(p2)), -1.f);              \
        float go = frcp(1.f + fexp2n(p3));                                         \
        cst = __builtin_fmaf(gf, cst, gi * gg);                                    \
        float th = __builtin_fmaf(2.f, frcp(1.f + fexp2n(cst * (2.f * LOG2E))), -1.f); \
        float h = go * th;                                                         \
        if (wr) {                                                                  \
          hb[buf ^ 1][u + 4 * (u >> 5)] = h;                                       \
          int step = 4 * cb + e;                                                   \
          int time = FWD ? step : 1023 - step;                                     \
          hout[(size_t)time * 256 + d * 125 + u] = h;                              \
        }                                                                          \
        barrier_lgkm();                                                            \
      }                                                                            \
      cur[0] = nxt[0]; cur[1] = nxt[1]; cur[2] = nxt[2]; cur[3] = nxt[3];          \
    }                                                                              \
  }

__global__ __launch_bounds__(512, 2) void k_rec(const float* __restrict__ Pq,
                                                const float* __restrict__ Whh,
                                                float* __restrict__ hout) {
  const int d = blockIdx.x;
  const int t = threadIdx.x;
  int u = t >> 2; if (u > 124) u = 124;
  const int sub = t & 3;
  const bool wr = (sub == 0) && ((t >> 2) < 125);

  // weights: 4 gate rows x 32 cols (sub chunk) -> 128 VGPRs, exp2-domain scaled
  const float* Wd = Whh + (size_t)d * 500 * 125;
  v2f w0[16], w1[16], w2[16], w3[16];
#pragma unroll
  for (int j = 0; j < 16; ++j) {
    int col = sub * 32 + 2 * j;
    const float* r0 = Wd + (size_t)(0 * 125 + u) * 125;
    const float* r1 = Wd + (size_t)(1 * 125 + u) * 125;
    const float* r2 = Wd + (size_t)(2 * 125 + u) * 125;
    const float* r3 = Wd + (size_t)(3 * 125 + u) * 125;
    bool c0 = col < 125, c1 = col + 1 < 125;
    v2f a, b, c, dd;
    a.x  = c0 ? r0[col] * LOG2E : 0.f;          a.y  = c1 ? r0[col + 1] * LOG2E : 0.f;
    b.x  = c0 ? r1[col] * LOG2E : 0.f;          b.y  = c1 ? r1[col + 1] * LOG2E : 0.f;
    c.x  = c0 ? r2[col] * 2.f * LOG2E : 0.f;    c.y  = c1 ? r2[col + 1] * 2.f * LOG2E : 0.f;
    dd.x = c0 ? r3[col] * LOG2E : 0.f;          dd.y = c1 ? r3[col + 1] * LOG2E : 0.f;
    w0[j] = a; w1[j] = b; w2[j] = c; w3[j] = dd;
  }

  __shared__ __align__(16) float hb[2][160];   // padded: addr(c)=c+4*(c>>5)
  for (int i = t; i < 320; i += 512) ((float*)hb)[i] = 0.f;

  const float4* Pr4 = (const float4*)(Pq + (size_t)d * 500 * 1024) + (size_t)u * 1024;

  if (d == 0) REC_BODY(1)
  else        REC_BODY(0)
}

// ---------------- pairwise scorer ---------------------------------------------------
__global__ __launch_bounds__(256) void k_pair(const float* __restrict__ AB,
    const float* __restrict__ fc2W, const float* __restrict__ fc2b,
    const float* __restrict__ sumw, float* __restrict__ outS,
    float* __restrict__ scoresT) {
  __shared__ float As[32][100];
  __shared__ float Bs[32][101];
  __shared__ float w2s[100];
  const int tid = threadIdx.x;
  const int i0 = blockIdx.y * 32, j0 = blockIdx.x * 32;
  for (int idx = tid; idx < 3200; idx += 256) {
    int r = idx / 100, k = idx - r * 100;
    As[r][k] = AB[(size_t)(i0 + r) * 200 + k];
    Bs[r][k] = AB[(size_t)(j0 + r) * 200 + 100 + k];
  }
  if (tid < 100) w2s[tid] = 2.f * fc2W[tid];
  __syncthreads();
  const int tx = tid & 31, ty = tid >> 5;
  float acc[4] = {0.f, 0.f, 0.f, 0.f};
#pragma unroll 4
  for (int k = 0; k < 100; ++k) {
    float b = Bs[tx][k];
    float wk2 = w2s[k];
    float bs = b * (2.f * LOG2E);
#pragma unroll
    for (int q = 0; q < 4; ++q) {
      float a = As[ty + 8 * q][k];
      float r = frcp(1.f + fexp2(__builtin_fmaf(a, 2.f * LOG2E, bs)));
      acc[q] = __builtin_fmaf(wk2, r, acc[q]);
    }
  }
  float base = sumw[0] + fc2b[0];
  const int j = j0 + tx;
#pragma unroll
  for (int q = 0; q < 4; ++q) {
    int i = i0 + ty + 8 * q;
    float val = (i != j && j != 0) ? (base - acc[q]) : 0.f;
    outS[(size_t)i * 1024 + j] = val;
    scoresT[(size_t)j * 1024 + i] = val;
  }
}

// ---------------- per-child log-softmax contribution -------------------------------
__global__ __launch_bounds__(256) void k_soft(const float* __restrict__ scoresT,
    const int* __restrict__ parents, float* __restrict__ contrib) {
  const int j = blockIdx.x, tid = threadIdx.x;
  __shared__ float red[256];
  const float* row = scoresT + (size_t)j * 1024;
  float v0 = row[tid], v1 = row[tid + 256], v2 = row[tid + 512], v3 = row[tid + 768];
  float m = fmaxf(fmaxf(v0, v1), fmaxf(v2, v3));
  red[tid] = m; __syncthreads();
  for (int off = 128; off; off >>= 1) {
    if (tid < off) red[tid] = fmaxf(red[tid], red[tid + off]);
    __syncthreads();
  }
  m = red[0]; __syncthreads();
  float s = fexp2((v0 - m) * LOG2E) + fexp2((v1 - m) * LOG2E) +
            fexp2((v2 - m) * LOG2E) + fexp2((v3 - m) * LOG2E);
  red[tid] = s; __syncthreads();
  for (int off = 128; off; off >>= 1) {
    if (tid < off) red[tid] += red[tid + off];
    __syncthreads();
  }
  if (tid == 0) {
    float S = red[0];
    int p = parents[j];
    contrib[j] = row[p] - m - flog2(S) * LN2;
  }
}

__global__ __launch_bounds__(256) void k_loss(const float* __restrict__ contrib,
                                              float* __restrict__ out) {
  __shared__ float red[256];
  int tid = threadIdx.x;
  float s = contrib[tid] + contrib[tid + 256] + contrib[tid + 512] + contrib[tid + 768];
  red[tid] = s; __syncthreads();
  for (int off = 128; off; off >>= 1) {
    if (tid < off) red[tid] += red[tid + off];
    __syncthreads();
  }
  if (tid == 0) out[0] = -red[0] * (1.f / 1024.f);
}

// ---------------- launcher ---------------------------------------------------------
extern "C" void kernel_launch(void* const* d_in, const int* in_sizes, int n_in,
                              void* d_out, int out_size, void* d_ws, size_t ws_size,
                              hipStream_t stream) {
  const float* wv   = (const float*)d_in[0];
  const int*   pidx = (const int*)d_in[1];
  const int*   par  = (const int*)d_in[2];
  const float* pemb = (const float*)d_in[3];
  const float* Wih0 = (const float*)d_in[4];
  const float* Whh0 = (const float*)d_in[5];
  const float* b0   = (const float*)d_in[6];
  const float* Wih1 = (const float*)d_in[7];
  const float* Whh1 = (const float*)d_in[8];
  const float* b1   = (const float*)d_in[9];
  const float* fc1W = (const float*)d_in[10];
  const float* fc1b = (const float*)d_in[11];
  const float* fc2W = (const float*)d_in[12];
  const float* fc2b = (const float*)d_in[13];
  float* ws = (float*)d_ws;
  // workspace layout (float offsets)
  float* X      = ws + 0;        // 1024*336
  float* Wih0p  = ws + 344064;   // 2*500*336
  float* Pq0    = ws + 680064;   // 2*125*1024*4 (gate-interleaved pre-gates L0)
  float* h0     = ws + 1704064;  // 1024*256
  float* Wih1p  = ws + 1966208;  // 2*500*256
  float* Pq1    = ws + 2222208;  // 2*125*1024*4 (gate-interleaved pre-gates L1)
  float* h1     = ws + 3246208;  // 1024*256
  float* Wab    = ws + 3508352;  // 200*256
  float* biasAB = ws + 3559552;  // 256
  float* AB     = ws + 3559808;  // 1024*200
  float* scT    = ws + 3764608;  // 1024*1024
  float* contrib= ws + 4813184;  // 1024
  float* sumw   = ws + 4814208;  // 1
  float* bs0    = ws + 4814212;  // 1000 (quarter-scaled biases L0)
  float* bs1    = ws + 4815212;  // 1000 (quarter-scaled biases L1)
  float* out = (float*)d_out;

  // zero padded h buffers (cols 250..255 must stay 0 for the K=256 GEMMs)
  hipMemsetAsync(h0, 0, 1024 * 256 * sizeof(float), stream);
  hipMemsetAsync(h1, 0, 1024 * 256 * sizeof(float), stream);

  k_embed <<<1024, 128, 0, stream>>>(wv, pidx, pemb, X);
  k_repack<<<1000, 128, 0, stream>>>(Wih0, Wih0p, 325, 336, 1);
  k_repack<<<1000, 128, 0, stream>>>(Wih1, Wih1p, 250, 256, 1);
  k_bscale<<<4, 256, 0, stream>>>(b0, bs0);
  k_bscale<<<4, 256, 0, stream>>>(b1, bs1);
  k_wab   <<<200, 128, 0, stream>>>(fc1W, Wab);
  k_misc  <<<1, 128, 0, stream>>>(fc1b, fc2W, biasAB, sumw);

  // layer 0 (pre-gates stored gate-interleaved: Pq[z][u][t][g])
  k_gemm<<<dim3(8, 16, 2), 256, 0, stream>>>(X, Wih0p, bs0, Pq0, 1024, 500, 336, 0,
                                             500L * 336, 500L * 1024, 500L, 2);
  k_rec <<<2, 512, 0, stream>>>(Pq0, Whh0, h0);
  // layer 1
  k_gemm<<<dim3(8, 16, 2), 256, 0, stream>>>(h0, Wih1p, bs1, Pq1, 1024, 500, 256, 0,
                                             500L * 256, 500L * 1024, 500L, 2);
  k_rec <<<2, 512, 0, stream>>>(Pq1, Whh1, h1);
  // head/child projections (fc1_b folded into head half via biasAB)
  k_gemm<<<dim3(4, 16, 1), 256, 0, stream>>>(h1, Wab, biasAB, AB, 1024, 200, 256, 200,
                                             0L, 0L, 0L, 0);
  // pairwise scores + transposed copy
  k_pair<<<dim3(32, 32), 256, 0, stream>>>(AB, fc2W, fc2b, sumw, out + 1, scT);
  // per-child log-softmax and loss
  k_soft<<<1024, 256, 0, stream>>>(scT, par, contrib);
  k_loss<<<1, 256, 0, stream>>>(contrib, out);
}